// Round 7
// baseline (450.395 us; speedup 1.0000x reference)
//
#include <hip/hip_runtime.h>
#include <math.h>

// GCN: h = D^-1/2 (A+I) D^-1/2 (x W) + b, 3 layers + classifier.
// N = 100000 nodes, E = 3.2M edges, feats 128 -> 4 -> 4 -> 2 -> 4.
//
// Round 7: aggp kernels were latency-bound with MLP~1 (4 dependent
// gather-iterations/thread; VALU 0.85%, HBM 4%). Fix: SPLIT 8->4 and
// batch-8 per thread -- 8 pairs loads then 8 independent Td gathers in
// flight before consumption (tail masked by x0.0 adds). part_kernel:
// wave-shfl scan (3 barriers/side instead of ~18) and short bucket-ids
// instead of gpos (LDS 40->30 KB, 4->5 blocks/CU).

#define OVF_CAP 32768
#define NBMAX   512      // max buckets (n <= 131072)
#define CHUNK   4096     // edges per partition block
#define CAPB    11776    // bucket capacity (expected 8192 uniform; 1.44x)
#define SPLIT   4        // agg sub-blocks per bucket

// ---------------- fast path ----------------

__global__ __launch_bounds__(256) void initc_kernel(int* __restrict__ curR, int* __restrict__ curC,
                                                    int* __restrict__ ovfRc, int* __restrict__ ovfCc, int B) {
    int i = blockIdx.x * blockDim.x + threadIdx.x;
    if (i == 0) { *ovfRc = 0; *ovfCc = 0; }
    if (i < B) { curR[i] = i * CAPB; curC[i] = i * CAPB; }
}

// Block-local counting sort per 4096-edge chunk, two phases:
//   R: bin by r>>8, payload ((r&255)<<24)|c into pairs[] (int)
//   C: bin by c>>8, payload c&255 into bufC8[] (byte)
__global__ __launch_bounds__(256) void part_kernel(const int* __restrict__ row, const int* __restrict__ col,
                                                   int* __restrict__ curR, int* __restrict__ curC,
                                                   int* __restrict__ pairs, unsigned char* __restrict__ bufC8,
                                                   int* __restrict__ ovfRc, int2* __restrict__ ovfR,
                                                   int* __restrict__ ovfCc, int* __restrict__ ovfC,
                                                   int B, int E) {
    __shared__ int hist[NBMAX];          // counts, then per-bucket cursor
    __shared__ int lbase[NBMAX];         // exclusive local base
    __shared__ int gbase[NBMAX];         // reserved global base
    __shared__ int waveSum[4];
    __shared__ int sVal[CHUNK];
    __shared__ unsigned short sBk[CHUNK];
    const int t = threadIdx.x;
    const int lane = t & 63, w = t >> 6;
    const long e0 = (long)blockIdx.x * CHUNK;
    int cnt_ch = (int)(E - e0); if (cnt_ch > CHUNK) cnt_ch = CHUNK; if (cnt_ch < 0) cnt_ch = 0;

    for (int side = 0; side < 2; ++side) {
        // --- histogram ---
        hist[2 * t] = 0; hist[2 * t + 1] = 0;
        __syncthreads();
        for (int k = t; k < cnt_ch; k += 256) {
            long e = e0 + k;
            int key = side == 0 ? row[e] : col[e];
            atomicAdd(&hist[key >> 8], 1);
        }
        __syncthreads();
        // --- wave-shfl exclusive scan (thread t owns buckets 2t, 2t+1) ---
        int h0 = hist[2 * t], h1 = hist[2 * t + 1];
        int sum = h0 + h1, sc = sum;
#pragma unroll
        for (int off = 1; off < 64; off <<= 1) {
            int u = __shfl_up(sc, off);
            if (lane >= off) sc += u;
        }
        if (lane == 63) waveSum[w] = sc;
        __syncthreads();
        int woff = 0;
        for (int i = 0; i < w; ++i) woff += waveSum[i];
        int excl = sc - sum + woff;
        lbase[2 * t] = excl;
        lbase[2 * t + 1] = excl + h0;
        int* cur = (side == 0) ? curR : curC;
        gbase[2 * t]     = h0 ? atomicAdd(&cur[2 * t], h0) : 0;
        gbase[2 * t + 1] = h1 ? atomicAdd(&cur[2 * t + 1], h1) : 0;
        hist[2 * t] = 0; hist[2 * t + 1] = 0;    // reuse as cursor
        __syncthreads();
        // --- sorted placement into LDS ---
        for (int k = t; k < cnt_ch; k += 256) {
            long e = e0 + k;
            int r = row[e], c = col[e];
            int key = side == 0 ? r : c;
            int bk = key >> 8;
            int rank = atomicAdd(&hist[bk], 1);
            int lpos = lbase[bk] + rank;
            int gpos = gbase[bk] + rank;
            if (gpos < (bk + 1) * CAPB) {
                sVal[lpos] = side == 0 ? (((r & 255) << 24) | c) : c;
                sBk[lpos] = (unsigned short)bk;
            } else {
                sBk[lpos] = 0xFFFF;
                if (side == 0) {
                    int i = atomicAdd(ovfRc, 1);
                    if (i < OVF_CAP) ovfR[i] = make_int2(r, c);
                } else {
                    int i = atomicAdd(ovfCc, 1);
                    if (i < OVF_CAP) ovfC[i] = c;
                }
            }
        }
        __syncthreads();
        // --- coalesced dump ---
        if (side == 0) {
            for (int k = t; k < cnt_ch; k += 256) {
                int bk = sBk[k];
                if (bk == 0xFFFF) continue;
                int g = gbase[bk] + (k - lbase[bk]);
                pairs[g] = sVal[k];
            }
        } else {
            for (int k = t; k < cnt_ch; k += 256) {
                int bk = sBk[k];
                if (bk == 0xFFFF) continue;
                int g = gbase[bk] + (k - lbase[bk]);
                bufC8[g] = (unsigned char)(sVal[k] & 255);
            }
        }
        __syncthreads();
    }
}

// deg from byte-binned copy: per-bucket LDS histogram, sequential write.
__global__ __launch_bounds__(256) void histo_kernel(const int* __restrict__ curC, const unsigned char* __restrict__ bufC8,
                                                    int* __restrict__ deg, int n) {
    __shared__ int h[256];
    const int b = blockIdx.x, t = threadIdx.x;
    h[t] = 0;
    __syncthreads();
    int base = b * CAPB;
    int cnt = curC[b] - base; if (cnt > CAPB) cnt = CAPB; if (cnt < 0) cnt = 0;
    for (int k = t; k < cnt; k += 256) atomicAdd(&h[bufC8[base + k]], 1);
    __syncthreads();
    int v = b * 256 + t;
    if (v < n) deg[v] = h[t];
}

__global__ __launch_bounds__(256) void ovfc_deg_kernel(const int* __restrict__ ovfCc, const int* __restrict__ ovfC,
                                                       int* __restrict__ deg) {
    int i = blockIdx.x * blockDim.x + threadIdx.x;
    int m = *ovfCc; if (m > OVF_CAP) m = OVF_CAP;
    if (i >= m) return;
    atomicAdd(&deg[ovfC[i]], 1);
}

// x [n,128] @ W1 [128,4] -> Td1 [n,4], pre-scaled by dinv[v]; also writes dinv.
__global__ __launch_bounds__(256) void mm1_kernel(const float* __restrict__ x, const float* __restrict__ W1,
                                                  const int* __restrict__ deg, float* __restrict__ dinv,
                                                  float4* __restrict__ Td1, int n) {
    int gid  = blockIdx.x * blockDim.x + threadIdx.x;
    int lane = threadIdx.x & 63;
    int v    = gid >> 6;
    if (v >= n) return;
    float2 xv = ((const float2*)x)[(size_t)v * 64 + lane];
    float4 wa = ((const float4*)W1)[2 * lane];
    float4 wb = ((const float4*)W1)[2 * lane + 1];
    float p0 = xv.x * wa.x + xv.y * wb.x;
    float p1 = xv.x * wa.y + xv.y * wb.y;
    float p2 = xv.x * wa.z + xv.y * wb.z;
    float p3 = xv.x * wa.w + xv.y * wb.w;
#pragma unroll
    for (int off = 32; off > 0; off >>= 1) {
        p0 += __shfl_xor(p0, off);
        p1 += __shfl_xor(p1, off);
        p2 += __shfl_xor(p2, off);
        p3 += __shfl_xor(p3, off);
    }
    if (lane == 0) {
        float d = rsqrtf((float)(deg[v] + 1));
        dinv[v] = d;
        Td1[v] = make_float4(p0 * d, p1 * d, p2 * d, p3 * d);
    }
}

// agg partial pass, 4-feat, batch-8: sub-block (b,s) accumulates its slice of
// bucket b into LDS with 8 gathers in flight, dumps dense partial. grid = B*SPLIT.
__global__ __launch_bounds__(256) void aggp4_kernel(const int* __restrict__ curR, const int* __restrict__ pairs,
                                                    const float4* __restrict__ Td, float* __restrict__ P) {
    __shared__ float acc[1024];
    const int t = threadIdx.x;
    const int b = blockIdx.x >> 2, s = blockIdx.x & 3;
    acc[t] = 0.f; acc[256 + t] = 0.f; acc[512 + t] = 0.f; acc[768 + t] = 0.f;
    __syncthreads();
    int base = b * CAPB;
    int cnt = curR[b] - base; if (cnt > CAPB) cnt = CAPB; if (cnt < 0) cnt = 0;
    int lo = base + (int)(((long)cnt * s) >> 2);
    int hi = base + (int)(((long)cnt * (s + 1)) >> 2);
    for (int k0 = lo + t; k0 < hi; k0 += 2048) {
        int p[8]; float m[8];
#pragma unroll
        for (int j = 0; j < 8; ++j) {
            int k = k0 + j * 256;
            int kc = k < hi ? k : (hi - 1);
            p[j] = pairs[kc];
            m[j] = k < hi ? 1.f : 0.f;
        }
        float4 tv[8];
#pragma unroll
        for (int j = 0; j < 8; ++j) tv[j] = Td[p[j] & 0xFFFFFF];
#pragma unroll
        for (int j = 0; j < 8; ++j) {
            int rl = ((unsigned)p[j]) >> 24;
            atomicAdd(&acc[rl],       tv[j].x * m[j]);
            atomicAdd(&acc[256 + rl], tv[j].y * m[j]);
            atomicAdd(&acc[512 + rl], tv[j].z * m[j]);
            atomicAdd(&acc[768 + rl], tv[j].w * m[j]);
        }
    }
    __syncthreads();
    float* Pb = P + ((size_t)blockIdx.x << 10);
    Pb[t] = acc[t]; Pb[256 + t] = acc[256 + t]; Pb[512 + t] = acc[512 + t]; Pb[768 + t] = acc[768 + t];
}

// 2-feat variant for layer 3.
__global__ __launch_bounds__(256) void aggp2_kernel(const int* __restrict__ curR, const int* __restrict__ pairs,
                                                    const float2* __restrict__ Td, float* __restrict__ P) {
    __shared__ float acc[512];
    const int t = threadIdx.x;
    const int b = blockIdx.x >> 2, s = blockIdx.x & 3;
    acc[t] = 0.f; acc[256 + t] = 0.f;
    __syncthreads();
    int base = b * CAPB;
    int cnt = curR[b] - base; if (cnt > CAPB) cnt = CAPB; if (cnt < 0) cnt = 0;
    int lo = base + (int)(((long)cnt * s) >> 2);
    int hi = base + (int)(((long)cnt * (s + 1)) >> 2);
    for (int k0 = lo + t; k0 < hi; k0 += 2048) {
        int p[8]; float m[8];
#pragma unroll
        for (int j = 0; j < 8; ++j) {
            int k = k0 + j * 256;
            int kc = k < hi ? k : (hi - 1);
            p[j] = pairs[kc];
            m[j] = k < hi ? 1.f : 0.f;
        }
        float2 tv[8];
#pragma unroll
        for (int j = 0; j < 8; ++j) tv[j] = Td[p[j] & 0xFFFFFF];
#pragma unroll
        for (int j = 0; j < 8; ++j) {
            int rl = ((unsigned)p[j]) >> 24;
            atomicAdd(&acc[rl],       tv[j].x * m[j]);
            atomicAdd(&acc[256 + rl], tv[j].y * m[j]);
        }
    }
    __syncthreads();
    float* Pb = P + ((size_t)blockIdx.x << 9);
    Pb[t] = acc[t]; Pb[256 + t] = acc[256 + t];
}

// merge 4 partials + overflow(rare) + layer-1 epilogue; Td2 = (h1@W2)*dinv.
__global__ __launch_bounds__(256) void merge1_kernel(const float* __restrict__ P, const float* __restrict__ dinv,
                                                     const float4* __restrict__ Td1,
                                                     const int* __restrict__ ovfRc, const int2* __restrict__ ovfR,
                                                     const float* __restrict__ b1, const float* __restrict__ W2,
                                                     float4* __restrict__ Td2, int n) {
    const int t = threadIdx.x;
    const int v = blockIdx.x * 256 + t;
    if (v >= n) return;
    const float* Pb = P + ((size_t)blockIdx.x << 12);
    float sx = 0.f, sy = 0.f, sz = 0.f, sw = 0.f;
#pragma unroll
    for (int s = 0; s < SPLIT; ++s) {
        sx += Pb[s * 1024 + t];
        sy += Pb[s * 1024 + 256 + t];
        sz += Pb[s * 1024 + 512 + t];
        sw += Pb[s * 1024 + 768 + t];
    }
    int m = *ovfRc; if (m > OVF_CAP) m = OVF_CAP;
    for (int i = 0; i < m; ++i) {                    // normally m == 0
        int2 rc = ovfR[i];
        if (rc.x == v) { float4 tv = Td1[rc.y]; sx += tv.x; sy += tv.y; sz += tv.z; sw += tv.w; }
    }
    float4 t0 = Td1[v];                              // self-loop
    sx += t0.x; sy += t0.y; sz += t0.z; sw += t0.w;
    float d = dinv[v];
    float h0 = tanhf(d * sx + b1[0]);
    float h1 = tanhf(d * sy + b1[1]);
    float h2 = tanhf(d * sz + b1[2]);
    float h3 = tanhf(d * sw + b1[3]);
    float4 o;
    o.x = (h0 * W2[0] + h1 * W2[4] + h2 * W2[8]  + h3 * W2[12]) * d;
    o.y = (h0 * W2[1] + h1 * W2[5] + h2 * W2[9]  + h3 * W2[13]) * d;
    o.z = (h0 * W2[2] + h1 * W2[6] + h2 * W2[10] + h3 * W2[14]) * d;
    o.w = (h0 * W2[3] + h1 * W2[7] + h2 * W2[11] + h3 * W2[15]) * d;
    Td2[v] = o;
}

__global__ __launch_bounds__(256) void merge2_kernel(const float* __restrict__ P, const float* __restrict__ dinv,
                                                     const float4* __restrict__ Td2,
                                                     const int* __restrict__ ovfRc, const int2* __restrict__ ovfR,
                                                     const float* __restrict__ b2, const float* __restrict__ W3,
                                                     float2* __restrict__ Td3, int n) {
    const int t = threadIdx.x;
    const int v = blockIdx.x * 256 + t;
    if (v >= n) return;
    const float* Pb = P + ((size_t)blockIdx.x << 12);
    float sx = 0.f, sy = 0.f, sz = 0.f, sw = 0.f;
#pragma unroll
    for (int s = 0; s < SPLIT; ++s) {
        sx += Pb[s * 1024 + t];
        sy += Pb[s * 1024 + 256 + t];
        sz += Pb[s * 1024 + 512 + t];
        sw += Pb[s * 1024 + 768 + t];
    }
    int m = *ovfRc; if (m > OVF_CAP) m = OVF_CAP;
    for (int i = 0; i < m; ++i) {
        int2 rc = ovfR[i];
        if (rc.x == v) { float4 tv = Td2[rc.y]; sx += tv.x; sy += tv.y; sz += tv.z; sw += tv.w; }
    }
    float4 t0 = Td2[v];
    sx += t0.x; sy += t0.y; sz += t0.z; sw += t0.w;
    float d = dinv[v];
    float h0 = tanhf(d * sx + b2[0]);
    float h1 = tanhf(d * sy + b2[1]);
    float h2 = tanhf(d * sz + b2[2]);
    float h3 = tanhf(d * sw + b2[3]);
    float2 o;
    o.x = (h0 * W3[0] + h1 * W3[2] + h2 * W3[4] + h3 * W3[6]) * d;
    o.y = (h0 * W3[1] + h1 * W3[3] + h2 * W3[5] + h3 * W3[7]) * d;
    Td3[v] = o;
}

__global__ __launch_bounds__(256) void merge3_kernel(const float* __restrict__ P, const float* __restrict__ dinv,
                                                     const float2* __restrict__ Td3,
                                                     const int* __restrict__ ovfRc, const int2* __restrict__ ovfR,
                                                     const float* __restrict__ b3, const float* __restrict__ Wc,
                                                     const float* __restrict__ bc, float* __restrict__ out, int n) {
    const int t = threadIdx.x;
    const int v = blockIdx.x * 256 + t;
    if (v >= n) return;
    const float* Pb = P + ((size_t)blockIdx.x << 11);
    float sx = 0.f, sy = 0.f;
#pragma unroll
    for (int s = 0; s < SPLIT; ++s) {
        sx += Pb[s * 512 + t];
        sy += Pb[s * 512 + 256 + t];
    }
    int m = *ovfRc; if (m > OVF_CAP) m = OVF_CAP;
    for (int i = 0; i < m; ++i) {
        int2 rc = ovfR[i];
        if (rc.x == v) { float2 tv = Td3[rc.y]; sx += tv.x; sy += tv.y; }
    }
    float2 t0 = Td3[v];
    sx += t0.x; sy += t0.y;
    float d = dinv[v];
    float h0 = tanhf(d * sx + b3[0]);
    float h1 = tanhf(d * sy + b3[1]);
    float4 o;
    o.x = h0 * Wc[0] + h1 * Wc[4] + bc[0];
    o.y = h0 * Wc[1] + h1 * Wc[5] + bc[1];
    o.z = h0 * Wc[2] + h1 * Wc[6] + bc[2];
    o.w = h0 * Wc[3] + h1 * Wc[7] + bc[3];
    ((float4*)out)[v] = o;
    ((float2*)(out + (size_t)n * 4))[v] = make_float2(h0, h1);
}

// ---------------- fallback path (round-2, proven) ----------------

#define ELL_C 64

__global__ __launch_bounds__(256) void zero_kernel(int* __restrict__ p, long count) {
    long i = (long)blockIdx.x * blockDim.x + threadIdx.x;
    if (i < count) p[i] = 0;
}
__global__ __launch_bounds__(256) void build_kernel(const int* __restrict__ row, const int* __restrict__ col,
                                                    int* __restrict__ deg, int* __restrict__ cnt,
                                                    int* __restrict__ slots, int* __restrict__ ovfc,
                                                    int2* __restrict__ ovf, int n, int E) {
    int e = blockIdx.x * blockDim.x + threadIdx.x;
    if (e >= E) return;
    int r = row[e], c = col[e];
    atomicAdd(&deg[c], 1);
    int pos = atomicAdd(&cnt[r], 1);
    if (pos < ELL_C) {
        slots[(size_t)pos * n + r] = c;
    } else {
        int i = atomicAdd(ovfc, 1);
        if (i < OVF_CAP) ovf[i] = make_int2(r, c);
    }
}
__global__ __launch_bounds__(256) void fb_mm1(const float* __restrict__ x, const float* __restrict__ W1,
                                              const int* __restrict__ deg, float* __restrict__ dinv,
                                              float4* __restrict__ A, int n) {
    int gid  = blockIdx.x * blockDim.x + threadIdx.x;
    int lane = threadIdx.x & 63;
    int v    = gid >> 6;
    if (v >= n) return;
    float2 xv = ((const float2*)x)[(size_t)v * 64 + lane];
    float4 wa = ((const float4*)W1)[2 * lane];
    float4 wb = ((const float4*)W1)[2 * lane + 1];
    float p0 = xv.x * wa.x + xv.y * wb.x;
    float p1 = xv.x * wa.y + xv.y * wb.y;
    float p2 = xv.x * wa.z + xv.y * wb.z;
    float p3 = xv.x * wa.w + xv.y * wb.w;
#pragma unroll
    for (int off = 32; off > 0; off >>= 1) {
        p0 += __shfl_xor(p0, off); p1 += __shfl_xor(p1, off);
        p2 += __shfl_xor(p2, off); p3 += __shfl_xor(p3, off);
    }
    if (lane == 0) {
        float d = rsqrtf((float)(deg[v] + 1));
        dinv[v] = d;
        A[v] = make_float4(p0 * d, p1 * d, p2 * d, p3 * d);
    }
}
__global__ __launch_bounds__(256) void ovf4_kernel(const int* __restrict__ ovfc, const int2* __restrict__ ovf,
                                                   const float4* __restrict__ Td, float* __restrict__ B) {
    int e = blockIdx.x * blockDim.x + threadIdx.x;
    int m = *ovfc; if (m > OVF_CAP) m = OVF_CAP;
    if (e >= m) return;
    int2 rc = ovf[e];
    float4 t = Td[rc.y];
    atomicAdd(&B[rc.x * 4 + 0], t.x);
    atomicAdd(&B[rc.x * 4 + 1], t.y);
    atomicAdd(&B[rc.x * 4 + 2], t.z);
    atomicAdd(&B[rc.x * 4 + 3], t.w);
}
__global__ __launch_bounds__(256) void ovf2_kernel(const int* __restrict__ ovfc, const int2* __restrict__ ovf,
                                                   const float2* __restrict__ Td, float* __restrict__ D) {
    int e = blockIdx.x * blockDim.x + threadIdx.x;
    int m = *ovfc; if (m > OVF_CAP) m = OVF_CAP;
    if (e >= m) return;
    int2 rc = ovf[e];
    float2 t = Td[rc.y];
    atomicAdd(&D[rc.x * 2 + 0], t.x);
    atomicAdd(&D[rc.x * 2 + 1], t.y);
}
__global__ __launch_bounds__(256) void agg_node1(const int* __restrict__ cnt, const int* __restrict__ slots,
                                                 const float* __restrict__ dinv, const float4* __restrict__ Td1,
                                                 float4* __restrict__ B, const float* __restrict__ b1,
                                                 const float* __restrict__ W2, float4* __restrict__ Td2, int n) {
    int v = blockIdx.x * blockDim.x + threadIdx.x;
    if (v >= n) return;
    int k = cnt[v]; if (k > ELL_C) k = ELL_C;
    float4 s = B[v];
    for (int j = 0; j < k; ++j) {
        int c = slots[(size_t)j * n + v];
        float4 t = Td1[c];
        s.x += t.x; s.y += t.y; s.z += t.z; s.w += t.w;
    }
    float4 t0 = Td1[v];
    s.x += t0.x; s.y += t0.y; s.z += t0.z; s.w += t0.w;
    float d = dinv[v];
    float h0 = tanhf(d * s.x + b1[0]);
    float h1 = tanhf(d * s.y + b1[1]);
    float h2 = tanhf(d * s.z + b1[2]);
    float h3 = tanhf(d * s.w + b1[3]);
    float4 o;
    o.x = (h0 * W2[0] + h1 * W2[4] + h2 * W2[8]  + h3 * W2[12]) * d;
    o.y = (h0 * W2[1] + h1 * W2[5] + h2 * W2[9]  + h3 * W2[13]) * d;
    o.z = (h0 * W2[2] + h1 * W2[6] + h2 * W2[10] + h3 * W2[14]) * d;
    o.w = (h0 * W2[3] + h1 * W2[7] + h2 * W2[11] + h3 * W2[15]) * d;
    Td2[v] = o;
    B[v] = make_float4(0.f, 0.f, 0.f, 0.f);
}
__global__ __launch_bounds__(256) void agg_node2(const int* __restrict__ cnt, const int* __restrict__ slots,
                                                 const float* __restrict__ dinv, const float4* __restrict__ Td2,
                                                 const float4* __restrict__ B, const float* __restrict__ b2,
                                                 const float* __restrict__ W3, float2* __restrict__ Td3, int n) {
    int v = blockIdx.x * blockDim.x + threadIdx.x;
    if (v >= n) return;
    int k = cnt[v]; if (k > ELL_C) k = ELL_C;
    float4 s = B[v];
    for (int j = 0; j < k; ++j) {
        int c = slots[(size_t)j * n + v];
        float4 t = Td2[c];
        s.x += t.x; s.y += t.y; s.z += t.z; s.w += t.w;
    }
    float4 t0 = Td2[v];
    s.x += t0.x; s.y += t0.y; s.z += t0.z; s.w += t0.w;
    float d = dinv[v];
    float h0 = tanhf(d * s.x + b2[0]);
    float h1 = tanhf(d * s.y + b2[1]);
    float h2 = tanhf(d * s.z + b2[2]);
    float h3 = tanhf(d * s.w + b2[3]);
    float2 o;
    o.x = (h0 * W3[0] + h1 * W3[2] + h2 * W3[4] + h3 * W3[6]) * d;
    o.y = (h0 * W3[1] + h1 * W3[3] + h2 * W3[5] + h3 * W3[7]) * d;
    Td3[v] = o;
}
__global__ __launch_bounds__(256) void agg_node3(const int* __restrict__ cnt, const int* __restrict__ slots,
                                                 const float* __restrict__ dinv, const float2* __restrict__ Td3,
                                                 const float2* __restrict__ D, const float* __restrict__ b3,
                                                 const float* __restrict__ Wc, const float* __restrict__ bc,
                                                 float* __restrict__ out, int n) {
    int v = blockIdx.x * blockDim.x + threadIdx.x;
    if (v >= n) return;
    int k = cnt[v]; if (k > ELL_C) k = ELL_C;
    float2 s = D[v];
    for (int j = 0; j < k; ++j) {
        int c = slots[(size_t)j * n + v];
        float2 t = Td3[c];
        s.x += t.x; s.y += t.y;
    }
    float2 t0 = Td3[v];
    s.x += t0.x; s.y += t0.y;
    float d = dinv[v];
    float h0 = tanhf(d * s.x + b3[0]);
    float h1 = tanhf(d * s.y + b3[1]);
    float4 o;
    o.x = h0 * Wc[0] + h1 * Wc[4] + bc[0];
    o.y = h0 * Wc[1] + h1 * Wc[5] + bc[1];
    o.z = h0 * Wc[2] + h1 * Wc[6] + bc[2];
    o.w = h0 * Wc[3] + h1 * Wc[7] + bc[3];
    ((float4*)out)[v] = o;
    ((float2*)(out + (size_t)n * 4))[v] = make_float2(h0, h1);
}

extern "C" void kernel_launch(void* const* d_in, const int* in_sizes, int n_in,
                              void* d_out, int out_size, void* d_ws, size_t ws_size,
                              hipStream_t stream) {
    const float* x  = (const float*)d_in[0];
    const int*   ei = (const int*)  d_in[1];
    const float* W1 = (const float*)d_in[2];
    const float* b1 = (const float*)d_in[3];
    const float* W2 = (const float*)d_in[4];
    const float* b2 = (const float*)d_in[5];
    const float* W3 = (const float*)d_in[6];
    const float* b3 = (const float*)d_in[7];
    const float* Wc = (const float*)d_in[8];
    const float* bc = (const float*)d_in[9];

    const size_t n = (size_t)(in_sizes[0] / 128);
    const int    E = in_sizes[1] / 2;
    const int* row = ei;       // destinations (segment ids)
    const int* col = ei + E;   // sources (gather)

    const int B     = (int)((n + 255) >> 8);
    const int nb_n  = (int)((n + 255) / 256);
    const int nb_e  = (E + 255) / 256;
    const int nb_mm = (int)((n * 64 + 255) / 256);
    const int nb_ov = OVF_CAP / 256;
    const int nb_p  = (E + CHUNK - 1) / CHUNK;

    int* ws = (int*)d_ws;

    // fast-path layout (ints):
    // pairs B*CAPB | U max(ceil(B*CAPB/4), 10n + B*SPLIT*1024) | dinv n | deg n |
    // curR B | curC B | ovfRc 1 | ovfCc 1 (+pad) | ovfR 2*OVF_CAP | ovfC OVF_CAP
    size_t uni = ((size_t)B * CAPB + 3) / 4;
    size_t td_plus_p = 10 * n + (size_t)B * SPLIT * 1024;
    if (uni < td_plus_p) uni = td_plus_p;
    size_t need_fast = ((size_t)B * CAPB + uni + 2 * n + 2 * (size_t)B + 4 + 3 * OVF_CAP) * 4 + 64;

    if (ws_size >= need_fast && n <= (1u << 24) && B <= NBMAX) {
        int*   pairs = ws;
        int*   U     = pairs + (size_t)B * CAPB;
        float* Td1   = (float*)U;                      // 4n
        float* Td2   = Td1 + 4 * n;                    // 4n
        float* Td3   = Td2 + 4 * n;                    // 2n
        float* P     = Td3 + 2 * n;                    // B*SPLIT*1024
        unsigned char* bufC8 = (unsigned char*)U;      // dead after histo (aliases Td)
        float* dinv  = (float*)(U + uni);              // n
        int*   deg   = (int*)(dinv + n);               // n
        int*   curR  = deg + n;                        // B
        int*   curC  = curR + B;                       // B
        int*   ovfRc = curC + B;                       // 1
        int*   ovfCc = ovfRc + 1;                      // 1
        int2*  ovfR  = (int2*)(ovfCc + 1);
        {   // ensure 8B alignment for int2
            size_t off = (size_t)(ovfCc + 1 - ws);
            if (off & 1) ovfR = (int2*)(ovfCc + 2);
        }
        int*   ovfC  = (int*)(ovfR + OVF_CAP);

        initc_kernel<<<(B + 255) / 256, 256, 0, stream>>>(curR, curC, ovfRc, ovfCc, B);
        part_kernel<<<nb_p, 256, 0, stream>>>(row, col, curR, curC, pairs, bufC8,
                                              ovfRc, ovfR, ovfCc, ovfC, B, E);
        histo_kernel<<<B, 256, 0, stream>>>(curC, bufC8, deg, (int)n);
        ovfc_deg_kernel<<<nb_ov, 256, 0, stream>>>(ovfCc, ovfC, deg);
        // bufC8 dead from here; Td + P region live.
        mm1_kernel<<<nb_mm, 256, 0, stream>>>(x, W1, deg, dinv, (float4*)Td1, (int)n);

        aggp4_kernel<<<B * SPLIT, 256, 0, stream>>>(curR, pairs, (const float4*)Td1, P);
        merge1_kernel<<<nb_n, 256, 0, stream>>>(P, dinv, (const float4*)Td1, ovfRc, ovfR, b1, W2, (float4*)Td2, (int)n);

        aggp4_kernel<<<B * SPLIT, 256, 0, stream>>>(curR, pairs, (const float4*)Td2, P);
        merge2_kernel<<<nb_n, 256, 0, stream>>>(P, dinv, (const float4*)Td2, ovfRc, ovfR, b2, W3, (float2*)Td3, (int)n);

        aggp2_kernel<<<B * SPLIT, 256, 0, stream>>>(curR, pairs, (const float2*)Td3, P);
        merge3_kernel<<<nb_n, 256, 0, stream>>>(P, dinv, (const float2*)Td3, ovfRc, ovfR, b3, Wc, bc, (float*)d_out, (int)n);
    } else {
        // fallback: round-2 ELL path (proven)
        float* fws  = (float*)d_ws;
        float* A1   = fws;
        float* A2   = A1 + 4 * n;
        float* C3   = A2 + 4 * n;
        float* Bv   = C3 + 2 * n;
        float* Dv   = Bv + 4 * n;
        float* dinv = Dv + 2 * n;
        int*   cnt  = (int*)(dinv + n);
        int*   deg  = cnt + n;
        int*   ovfc = deg + n;
        int2*  ovf  = (int2*)(ovfc + 4);
        int*   slots = (int*)(ovf + OVF_CAP);

        long zc = (long)(9 * n + 4);
        zero_kernel<<<(int)((zc + 255) / 256), 256, 0, stream>>>((int*)Bv, zc);
        build_kernel<<<nb_e, 256, 0, stream>>>(row, col, deg, cnt, slots, ovfc, ovf, (int)n, E);
        fb_mm1<<<nb_mm, 256, 0, stream>>>(x, W1, deg, dinv, (float4*)A1, (int)n);
        ovf4_kernel<<<nb_ov, 256, 0, stream>>>(ovfc, ovf, (const float4*)A1, Bv);
        agg_node1<<<nb_n, 256, 0, stream>>>(cnt, slots, dinv, (const float4*)A1, (float4*)Bv, b1, W2, (float4*)A2, (int)n);
        ovf4_kernel<<<nb_ov, 256, 0, stream>>>(ovfc, ovf, (const float4*)A2, Bv);
        agg_node2<<<nb_n, 256, 0, stream>>>(cnt, slots, dinv, (const float4*)A2, (const float4*)Bv, b2, W3, (float2*)C3, (int)n);
        ovf2_kernel<<<nb_ov, 256, 0, stream>>>(ovfc, ovf, (const float2*)C3, Dv);
        agg_node3<<<nb_n, 256, 0, stream>>>(cnt, slots, dinv, (const float2*)C3, (const float2*)Dv, b3, Wc, bc, (float*)d_out, (int)n);
    }
}

// Round 9
// 430.253 us; speedup vs baseline: 1.0468x; 1.0468x over previous
//
#include <hip/hip_runtime.h>
#include <math.h>

// GCN: h = D^-1/2 (A+I) D^-1/2 (x W) + b, 3 layers + classifier.
// N = 100000 nodes, E = 3.2M edges, feats 128 -> 4 -> 4 -> 2 -> 4.
//
// Round 9 = round 8 resubmit with scalar-only nontemporal builtins (the
// ext_vector nt forms may have tripped the harness compiler; no diagnostics
// came back). Model: aggp is MSHR-bound: 3.2M gathers x ~900cyc latency /
// (64 MSHR x 256 CU x 2.4GHz) = 73us = measured. 900cyc = dirty-remote
// path (Td freshly written in other XCDs' L2s). NT producer stores keep
// Td/pairs/P clean in memory-side so consumer XCDs can cache them locally.

#define OVF_CAP 32768
#define NBMAX   512      // max buckets (n <= 131072)
#define CHUNK   4096     // edges per partition block
#define CAPB    11776    // bucket capacity (expected 8192 uniform; 1.44x)
#define SPLIT   4        // agg sub-blocks per bucket

// ---------------- fast path ----------------

__global__ __launch_bounds__(256) void initc_kernel(int* __restrict__ curR, int* __restrict__ curC,
                                                    int* __restrict__ ovfRc, int* __restrict__ ovfCc, int B) {
    int i = blockIdx.x * blockDim.x + threadIdx.x;
    if (i == 0) { *ovfRc = 0; *ovfCc = 0; }
    if (i < B) { curR[i] = i * CAPB; curC[i] = i * CAPB; }
}

// Block-local counting sort per 4096-edge chunk (round-6 proven structure):
//   R: bin by r>>8, payload ((r&255)<<24)|c into pairs[] (int)
//   C: bin by c>>8, payload c&255 into bufC8[] (byte)
__global__ __launch_bounds__(256) void part_kernel(const int* __restrict__ row, const int* __restrict__ col,
                                                   int* __restrict__ curR, int* __restrict__ curC,
                                                   int* __restrict__ pairs, unsigned char* __restrict__ bufC8,
                                                   int* __restrict__ ovfRc, int2* __restrict__ ovfR,
                                                   int* __restrict__ ovfCc, int* __restrict__ ovfC,
                                                   int B, int E) {
    __shared__ int hist[NBMAX];      // counts, then per-bucket cursor
    __shared__ int gbase[NBMAX];     // reserved global base
    __shared__ int sA[NBMAX];        // scan ping / final local base
    __shared__ int sB[NBMAX];        // scan pong
    __shared__ int sVal[CHUNK];
    __shared__ int sGpos[CHUNK];
    const int t = threadIdx.x;
    const long e0 = (long)blockIdx.x * CHUNK;
    int cnt_ch = (int)(E - e0); if (cnt_ch > CHUNK) cnt_ch = CHUNK; if (cnt_ch < 0) cnt_ch = 0;

    for (int side = 0; side < 2; ++side) {
        // --- histogram ---
        for (int i = t; i < NBMAX; i += 256) hist[i] = 0;
        __syncthreads();
        for (int k = t; k < cnt_ch; k += 256) {
            long e = e0 + k;
            int key = side == 0 ? row[e] : col[e];
            atomicAdd(&hist[key >> 8], 1);
        }
        __syncthreads();
        // --- inclusive scan (Hillis-Steele, NBMAX wide) ---
        for (int i = t; i < NBMAX; i += 256) sA[i] = hist[i];
        __syncthreads();
        int* a = sA; int* b = sB;
        for (int off = 1; off < NBMAX; off <<= 1) {
            for (int i = t; i < NBMAX; i += 256)
                b[i] = a[i] + (i >= off ? a[i - off] : 0);
            __syncthreads();
            int* tmp = a; a = b; b = tmp;
        }
        // reserve global runs; make exclusive base; reset cursor.
        int* cur = (side == 0) ? curR : curC;
        for (int i = t; i < NBMAX; i += 256) {
            int cntb = hist[i];
            gbase[i] = cntb ? atomicAdd(&cur[i], cntb) : 0;
            b[i] = a[i] - cntb;              // exclusive local base (in b[])
            hist[i] = 0;                     // reuse as cursor
        }
        __syncthreads();
        // --- sorted placement into LDS ---
        for (int k = t; k < cnt_ch; k += 256) {
            long e = e0 + k;
            int r = row[e], c = col[e];
            int key = side == 0 ? r : c;
            int bk = key >> 8;
            int rank = atomicAdd(&hist[bk], 1);
            int lpos = b[bk] + rank;
            int gpos = gbase[bk] + rank;
            if (gpos < (bk + 1) * CAPB) {
                sVal[lpos] = side == 0 ? (((r & 255) << 24) | c) : c;
                sGpos[lpos] = gpos;
            } else {
                sVal[lpos] = 0;
                sGpos[lpos] = -1;
                if (side == 0) {
                    int i = atomicAdd(ovfRc, 1);
                    if (i < OVF_CAP) ovfR[i] = make_int2(r, c);
                } else {
                    int i = atomicAdd(ovfCc, 1);
                    if (i < OVF_CAP) ovfC[i] = c;
                }
            }
        }
        __syncthreads();
        // --- coalesced dump (non-temporal: keep lines clean for consumers) ---
        if (side == 0) {
            for (int k = t; k < cnt_ch; k += 256) {
                int g = sGpos[k];
                if (g >= 0) __builtin_nontemporal_store(sVal[k], &pairs[g]);
            }
        } else {
            for (int k = t; k < cnt_ch; k += 256) {
                int g = sGpos[k];
                if (g >= 0) __builtin_nontemporal_store((unsigned char)(sVal[k] & 255), &bufC8[g]);
            }
        }
        __syncthreads();
    }
}

// deg from byte-binned copy: per-bucket LDS histogram, sequential write.
__global__ __launch_bounds__(256) void histo_kernel(const int* __restrict__ curC, const unsigned char* __restrict__ bufC8,
                                                    int* __restrict__ deg, int n) {
    __shared__ int h[256];
    const int b = blockIdx.x, t = threadIdx.x;
    h[t] = 0;
    __syncthreads();
    int base = b * CAPB;
    int cnt = curC[b] - base; if (cnt > CAPB) cnt = CAPB; if (cnt < 0) cnt = 0;
    for (int k = t; k < cnt; k += 256) atomicAdd(&h[__builtin_nontemporal_load(&bufC8[base + k])], 1);
    __syncthreads();
    int v = b * 256 + t;
    if (v < n) __builtin_nontemporal_store(h[t], &deg[v]);
}

__global__ __launch_bounds__(256) void ovfc_deg_kernel(const int* __restrict__ ovfCc, const int* __restrict__ ovfC,
                                                       int* __restrict__ deg) {
    int i = blockIdx.x * blockDim.x + threadIdx.x;
    int m = *ovfCc; if (m > OVF_CAP) m = OVF_CAP;
    if (i >= m) return;
    atomicAdd(&deg[ovfC[i]], 1);
}

// x [n,128] @ W1 [128,4] -> Td1 [n,4], pre-scaled by dinv[v]; also writes dinv.
__global__ __launch_bounds__(256) void mm1_kernel(const float* __restrict__ x, const float* __restrict__ W1,
                                                  const int* __restrict__ deg, float* __restrict__ dinv,
                                                  float* __restrict__ Td1, int n) {
    int gid  = blockIdx.x * blockDim.x + threadIdx.x;
    int lane = threadIdx.x & 63;
    int v    = gid >> 6;
    if (v >= n) return;
    float2 xv = ((const float2*)x)[(size_t)v * 64 + lane];
    float4 wa = ((const float4*)W1)[2 * lane];
    float4 wb = ((const float4*)W1)[2 * lane + 1];
    float p0 = xv.x * wa.x + xv.y * wb.x;
    float p1 = xv.x * wa.y + xv.y * wb.y;
    float p2 = xv.x * wa.z + xv.y * wb.z;
    float p3 = xv.x * wa.w + xv.y * wb.w;
#pragma unroll
    for (int off = 32; off > 0; off >>= 1) {
        p0 += __shfl_xor(p0, off);
        p1 += __shfl_xor(p1, off);
        p2 += __shfl_xor(p2, off);
        p3 += __shfl_xor(p3, off);
    }
    if (lane == 0) {
        float d = rsqrtf((float)(deg[v] + 1));
        __builtin_nontemporal_store(d, &dinv[v]);
        __builtin_nontemporal_store(p0 * d, &Td1[4 * (size_t)v + 0]);
        __builtin_nontemporal_store(p1 * d, &Td1[4 * (size_t)v + 1]);
        __builtin_nontemporal_store(p2 * d, &Td1[4 * (size_t)v + 2]);
        __builtin_nontemporal_store(p3 * d, &Td1[4 * (size_t)v + 3]);
    }
}

// agg partial pass, 4-feat, batch-8: sub-block (b,s) accumulates its slice of
// bucket b into LDS, dumps dense partial. Td reads NORMAL (want local-L2
// caching of clean lines); pairs nt-load (stream once); P nt-store.
__global__ __launch_bounds__(256) void aggp4_kernel(const int* __restrict__ curR, const int* __restrict__ pairs,
                                                    const float4* __restrict__ Td, float* __restrict__ P) {
    __shared__ float acc[1024];
    const int t = threadIdx.x;
    const int b = blockIdx.x >> 2, s = blockIdx.x & 3;
    acc[t] = 0.f; acc[256 + t] = 0.f; acc[512 + t] = 0.f; acc[768 + t] = 0.f;
    __syncthreads();
    int base = b * CAPB;
    int cnt = curR[b] - base; if (cnt > CAPB) cnt = CAPB; if (cnt < 0) cnt = 0;
    int lo = base + (int)(((long)cnt * s) >> 2);
    int hi = base + (int)(((long)cnt * (s + 1)) >> 2);
    for (int k0 = lo + t; k0 < hi; k0 += 2048) {
        int p[8]; float m[8];
#pragma unroll
        for (int j = 0; j < 8; ++j) {
            int k = k0 + j * 256;
            int kc = k < hi ? k : (hi - 1);
            p[j] = __builtin_nontemporal_load(&pairs[kc]);
            m[j] = k < hi ? 1.f : 0.f;
        }
        float4 tv[8];
#pragma unroll
        for (int j = 0; j < 8; ++j) tv[j] = Td[p[j] & 0xFFFFFF];
#pragma unroll
        for (int j = 0; j < 8; ++j) {
            int rl = ((unsigned)p[j]) >> 24;
            atomicAdd(&acc[rl],       tv[j].x * m[j]);
            atomicAdd(&acc[256 + rl], tv[j].y * m[j]);
            atomicAdd(&acc[512 + rl], tv[j].z * m[j]);
            atomicAdd(&acc[768 + rl], tv[j].w * m[j]);
        }
    }
    __syncthreads();
    float* Pb = P + ((size_t)blockIdx.x << 10);
    __builtin_nontemporal_store(acc[t],       &Pb[t]);
    __builtin_nontemporal_store(acc[256 + t], &Pb[256 + t]);
    __builtin_nontemporal_store(acc[512 + t], &Pb[512 + t]);
    __builtin_nontemporal_store(acc[768 + t], &Pb[768 + t]);
}

// 2-feat variant for layer 3.
__global__ __launch_bounds__(256) void aggp2_kernel(const int* __restrict__ curR, const int* __restrict__ pairs,
                                                    const float2* __restrict__ Td, float* __restrict__ P) {
    __shared__ float acc[512];
    const int t = threadIdx.x;
    const int b = blockIdx.x >> 2, s = blockIdx.x & 3;
    acc[t] = 0.f; acc[256 + t] = 0.f;
    __syncthreads();
    int base = b * CAPB;
    int cnt = curR[b] - base; if (cnt > CAPB) cnt = CAPB; if (cnt < 0) cnt = 0;
    int lo = base + (int)(((long)cnt * s) >> 2);
    int hi = base + (int)(((long)cnt * (s + 1)) >> 2);
    for (int k0 = lo + t; k0 < hi; k0 += 2048) {
        int p[8]; float m[8];
#pragma unroll
        for (int j = 0; j < 8; ++j) {
            int k = k0 + j * 256;
            int kc = k < hi ? k : (hi - 1);
            p[j] = __builtin_nontemporal_load(&pairs[kc]);
            m[j] = k < hi ? 1.f : 0.f;
        }
        float2 tv[8];
#pragma unroll
        for (int j = 0; j < 8; ++j) tv[j] = Td[p[j] & 0xFFFFFF];
#pragma unroll
        for (int j = 0; j < 8; ++j) {
            int rl = ((unsigned)p[j]) >> 24;
            atomicAdd(&acc[rl],       tv[j].x * m[j]);
            atomicAdd(&acc[256 + rl], tv[j].y * m[j]);
        }
    }
    __syncthreads();
    float* Pb = P + ((size_t)blockIdx.x << 9);
    __builtin_nontemporal_store(acc[t],       &Pb[t]);
    __builtin_nontemporal_store(acc[256 + t], &Pb[256 + t]);
}

// merge 4 partials + overflow(rare) + layer-1 epilogue; Td2 = (h1@W2)*dinv.
__global__ __launch_bounds__(256) void merge1_kernel(const float* __restrict__ P, const float* __restrict__ dinv,
                                                     const float4* __restrict__ Td1,
                                                     const int* __restrict__ ovfRc, const int2* __restrict__ ovfR,
                                                     const float* __restrict__ b1, const float* __restrict__ W2,
                                                     float* __restrict__ Td2, int n) {
    const int t = threadIdx.x;
    const int v = blockIdx.x * 256 + t;
    if (v >= n) return;
    const float* Pb = P + ((size_t)blockIdx.x << 12);
    float sx = 0.f, sy = 0.f, sz = 0.f, sw = 0.f;
#pragma unroll
    for (int s = 0; s < SPLIT; ++s) {
        sx += __builtin_nontemporal_load(&Pb[s * 1024 + t]);
        sy += __builtin_nontemporal_load(&Pb[s * 1024 + 256 + t]);
        sz += __builtin_nontemporal_load(&Pb[s * 1024 + 512 + t]);
        sw += __builtin_nontemporal_load(&Pb[s * 1024 + 768 + t]);
    }
    int m = *ovfRc; if (m > OVF_CAP) m = OVF_CAP;
    for (int i = 0; i < m; ++i) {                    // normally m == 0
        int2 rc = ovfR[i];
        if (rc.x == v) { float4 tv = Td1[rc.y]; sx += tv.x; sy += tv.y; sz += tv.z; sw += tv.w; }
    }
    float4 t0 = Td1[v];                              // self-loop
    sx += t0.x; sy += t0.y; sz += t0.z; sw += t0.w;
    float d = dinv[v];
    float h0 = tanhf(d * sx + b1[0]);
    float h1 = tanhf(d * sy + b1[1]);
    float h2 = tanhf(d * sz + b1[2]);
    float h3 = tanhf(d * sw + b1[3]);
    __builtin_nontemporal_store((h0 * W2[0] + h1 * W2[4] + h2 * W2[8]  + h3 * W2[12]) * d, &Td2[4 * (size_t)v + 0]);
    __builtin_nontemporal_store((h0 * W2[1] + h1 * W2[5] + h2 * W2[9]  + h3 * W2[13]) * d, &Td2[4 * (size_t)v + 1]);
    __builtin_nontemporal_store((h0 * W2[2] + h1 * W2[6] + h2 * W2[10] + h3 * W2[14]) * d, &Td2[4 * (size_t)v + 2]);
    __builtin_nontemporal_store((h0 * W2[3] + h1 * W2[7] + h2 * W2[11] + h3 * W2[15]) * d, &Td2[4 * (size_t)v + 3]);
}

__global__ __launch_bounds__(256) void merge2_kernel(const float* __restrict__ P, const float* __restrict__ dinv,
                                                     const float4* __restrict__ Td2,
                                                     const int* __restrict__ ovfRc, const int2* __restrict__ ovfR,
                                                     const float* __restrict__ b2, const float* __restrict__ W3,
                                                     float* __restrict__ Td3, int n) {
    const int t = threadIdx.x;
    const int v = blockIdx.x * 256 + t;
    if (v >= n) return;
    const float* Pb = P + ((size_t)blockIdx.x << 12);
    float sx = 0.f, sy = 0.f, sz = 0.f, sw = 0.f;
#pragma unroll
    for (int s = 0; s < SPLIT; ++s) {
        sx += __builtin_nontemporal_load(&Pb[s * 1024 + t]);
        sy += __builtin_nontemporal_load(&Pb[s * 1024 + 256 + t]);
        sz += __builtin_nontemporal_load(&Pb[s * 1024 + 512 + t]);
        sw += __builtin_nontemporal_load(&Pb[s * 1024 + 768 + t]);
    }
    int m = *ovfRc; if (m > OVF_CAP) m = OVF_CAP;
    for (int i = 0; i < m; ++i) {
        int2 rc = ovfR[i];
        if (rc.x == v) { float4 tv = Td2[rc.y]; sx += tv.x; sy += tv.y; sz += tv.z; sw += tv.w; }
    }
    float4 t0 = Td2[v];
    sx += t0.x; sy += t0.y; sz += t0.z; sw += t0.w;
    float d = dinv[v];
    float h0 = tanhf(d * sx + b2[0]);
    float h1 = tanhf(d * sy + b2[1]);
    float h2 = tanhf(d * sz + b2[2]);
    float h3 = tanhf(d * sw + b2[3]);
    __builtin_nontemporal_store((h0 * W3[0] + h1 * W3[2] + h2 * W3[4] + h3 * W3[6]) * d, &Td3[2 * (size_t)v + 0]);
    __builtin_nontemporal_store((h0 * W3[1] + h1 * W3[3] + h2 * W3[5] + h3 * W3[7]) * d, &Td3[2 * (size_t)v + 1]);
}

__global__ __launch_bounds__(256) void merge3_kernel(const float* __restrict__ P, const float* __restrict__ dinv,
                                                     const float2* __restrict__ Td3,
                                                     const int* __restrict__ ovfRc, const int2* __restrict__ ovfR,
                                                     const float* __restrict__ b3, const float* __restrict__ Wc,
                                                     const float* __restrict__ bc, float* __restrict__ out, int n) {
    const int t = threadIdx.x;
    const int v = blockIdx.x * 256 + t;
    if (v >= n) return;
    const float* Pb = P + ((size_t)blockIdx.x << 11);
    float sx = 0.f, sy = 0.f;
#pragma unroll
    for (int s = 0; s < SPLIT; ++s) {
        sx += __builtin_nontemporal_load(&Pb[s * 512 + t]);
        sy += __builtin_nontemporal_load(&Pb[s * 512 + 256 + t]);
    }
    int m = *ovfRc; if (m > OVF_CAP) m = OVF_CAP;
    for (int i = 0; i < m; ++i) {
        int2 rc = ovfR[i];
        if (rc.x == v) { float2 tv = Td3[rc.y]; sx += tv.x; sy += tv.y; }
    }
    float2 t0 = Td3[v];
    sx += t0.x; sy += t0.y;
    float d = dinv[v];
    float h0 = tanhf(d * sx + b3[0]);
    float h1 = tanhf(d * sy + b3[1]);
    float4 o;
    o.x = h0 * Wc[0] + h1 * Wc[4] + bc[0];
    o.y = h0 * Wc[1] + h1 * Wc[5] + bc[1];
    o.z = h0 * Wc[2] + h1 * Wc[6] + bc[2];
    o.w = h0 * Wc[3] + h1 * Wc[7] + bc[3];
    ((float4*)out)[v] = o;
    ((float2*)(out + (size_t)n * 4))[v] = make_float2(h0, h1);
}

// ---------------- fallback path (round-2, proven) ----------------

#define ELL_C 64

__global__ __launch_bounds__(256) void zero_kernel(int* __restrict__ p, long count) {
    long i = (long)blockIdx.x * blockDim.x + threadIdx.x;
    if (i < count) p[i] = 0;
}
__global__ __launch_bounds__(256) void build_kernel(const int* __restrict__ row, const int* __restrict__ col,
                                                    int* __restrict__ deg, int* __restrict__ cnt,
                                                    int* __restrict__ slots, int* __restrict__ ovfc,
                                                    int2* __restrict__ ovf, int n, int E) {
    int e = blockIdx.x * blockDim.x + threadIdx.x;
    if (e >= E) return;
    int r = row[e], c = col[e];
    atomicAdd(&deg[c], 1);
    int pos = atomicAdd(&cnt[r], 1);
    if (pos < ELL_C) {
        slots[(size_t)pos * n + r] = c;
    } else {
        int i = atomicAdd(ovfc, 1);
        if (i < OVF_CAP) ovf[i] = make_int2(r, c);
    }
}
__global__ __launch_bounds__(256) void fb_mm1(const float* __restrict__ x, const float* __restrict__ W1,
                                              const int* __restrict__ deg, float* __restrict__ dinv,
                                              float4* __restrict__ A, int n) {
    int gid  = blockIdx.x * blockDim.x + threadIdx.x;
    int lane = threadIdx.x & 63;
    int v    = gid >> 6;
    if (v >= n) return;
    float2 xv = ((const float2*)x)[(size_t)v * 64 + lane];
    float4 wa = ((const float4*)W1)[2 * lane];
    float4 wb = ((const float4*)W1)[2 * lane + 1];
    float p0 = xv.x * wa.x + xv.y * wb.x;
    float p1 = xv.x * wa.y + xv.y * wb.y;
    float p2 = xv.x * wa.z + xv.y * wb.z;
    float p3 = xv.x * wa.w + xv.y * wb.w;
#pragma unroll
    for (int off = 32; off > 0; off >>= 1) {
        p0 += __shfl_xor(p0, off); p1 += __shfl_xor(p1, off);
        p2 += __shfl_xor(p2, off); p3 += __shfl_xor(p3, off);
    }
    if (lane == 0) {
        float d = rsqrtf((float)(deg[v] + 1));
        dinv[v] = d;
        A[v] = make_float4(p0 * d, p1 * d, p2 * d, p3 * d);
    }
}
__global__ __launch_bounds__(256) void ovf4_kernel(const int* __restrict__ ovfc, const int2* __restrict__ ovf,
                                                   const float4* __restrict__ Td, float* __restrict__ B) {
    int e = blockIdx.x * blockDim.x + threadIdx.x;
    int m = *ovfc; if (m > OVF_CAP) m = OVF_CAP;
    if (e >= m) return;
    int2 rc = ovf[e];
    float4 t = Td[rc.y];
    atomicAdd(&B[rc.x * 4 + 0], t.x);
    atomicAdd(&B[rc.x * 4 + 1], t.y);
    atomicAdd(&B[rc.x * 4 + 2], t.z);
    atomicAdd(&B[rc.x * 4 + 3], t.w);
}
__global__ __launch_bounds__(256) void ovf2_kernel(const int* __restrict__ ovfc, const int2* __restrict__ ovf,
                                                   const float2* __restrict__ Td, float* __restrict__ D) {
    int e = blockIdx.x * blockDim.x + threadIdx.x;
    int m = *ovfc; if (m > OVF_CAP) m = OVF_CAP;
    if (e >= m) return;
    int2 rc = ovf[e];
    float2 t = Td[rc.y];
    atomicAdd(&D[rc.x * 2 + 0], t.x);
    atomicAdd(&D[rc.x * 2 + 1], t.y);
}
__global__ __launch_bounds__(256) void agg_node1(const int* __restrict__ cnt, const int* __restrict__ slots,
                                                 const float* __restrict__ dinv, const float4* __restrict__ Td1,
                                                 float4* __restrict__ B, const float* __restrict__ b1,
                                                 const float* __restrict__ W2, float4* __restrict__ Td2, int n) {
    int v = blockIdx.x * blockDim.x + threadIdx.x;
    if (v >= n) return;
    int k = cnt[v]; if (k > ELL_C) k = ELL_C;
    float4 s = B[v];
    for (int j = 0; j < k; ++j) {
        int c = slots[(size_t)j * n + v];
        float4 t = Td1[c];
        s.x += t.x; s.y += t.y; s.z += t.z; s.w += t.w;
    }
    float4 t0 = Td1[v];
    s.x += t0.x; s.y += t0.y; s.z += t0.z; s.w += t0.w;
    float d = dinv[v];
    float h0 = tanhf(d * s.x + b1[0]);
    float h1 = tanhf(d * s.y + b1[1]);
    float h2 = tanhf(d * s.z + b1[2]);
    float h3 = tanhf(d * s.w + b1[3]);
    float4 o;
    o.x = (h0 * W2[0] + h1 * W2[4] + h2 * W2[8]  + h3 * W2[12]) * d;
    o.y = (h0 * W2[1] + h1 * W2[5] + h2 * W2[9]  + h3 * W2[13]) * d;
    o.z = (h0 * W2[2] + h1 * W2[6] + h2 * W2[10] + h3 * W2[14]) * d;
    o.w = (h0 * W2[3] + h1 * W2[7] + h2 * W2[11] + h3 * W2[15]) * d;
    Td2[v] = o;
    B[v] = make_float4(0.f, 0.f, 0.f, 0.f);
}
__global__ __launch_bounds__(256) void agg_node2(const int* __restrict__ cnt, const int* __restrict__ slots,
                                                 const float* __restrict__ dinv, const float4* __restrict__ Td2,
                                                 const float4* __restrict__ B, const float* __restrict__ b2,
                                                 const float* __restrict__ W3, float2* __restrict__ Td3, int n) {
    int v = blockIdx.x * blockDim.x + threadIdx.x;
    if (v >= n) return;
    int k = cnt[v]; if (k > ELL_C) k = ELL_C;
    float4 s = B[v];
    for (int j = 0; j < k; ++j) {
        int c = slots[(size_t)j * n + v];
        float4 t = Td2[c];
        s.x += t.x; s.y += t.y; s.z += t.z; s.w += t.w;
    }
    float4 t0 = Td2[v];
    s.x += t0.x; s.y += t0.y; s.z += t0.z; s.w += t0.w;
    float d = dinv[v];
    float h0 = tanhf(d * s.x + b2[0]);
    float h1 = tanhf(d * s.y + b2[1]);
    float h2 = tanhf(d * s.z + b2[2]);
    float h3 = tanhf(d * s.w + b2[3]);
    float2 o;
    o.x = (h0 * W3[0] + h1 * W3[2] + h2 * W3[4] + h3 * W3[6]) * d;
    o.y = (h0 * W3[1] + h1 * W3[3] + h2 * W3[5] + h3 * W3[7]) * d;
    Td3[v] = o;
}
__global__ __launch_bounds__(256) void agg_node3(const int* __restrict__ cnt, const int* __restrict__ slots,
                                                 const float* __restrict__ dinv, const float2* __restrict__ Td3,
                                                 const float2* __restrict__ D, const float* __restrict__ b3,
                                                 const float* __restrict__ Wc, const float* __restrict__ bc,
                                                 float* __restrict__ out, int n) {
    int v = blockIdx.x * blockDim.x + threadIdx.x;
    if (v >= n) return;
    int k = cnt[v]; if (k > ELL_C) k = ELL_C;
    float2 s = D[v];
    for (int j = 0; j < k; ++j) {
        int c = slots[(size_t)j * n + v];
        float2 t = Td3[c];
        s.x += t.x; s.y += t.y;
    }
    float2 t0 = Td3[v];
    s.x += t0.x; s.y += t0.y;
    float d = dinv[v];
    float h0 = tanhf(d * s.x + b3[0]);
    float h1 = tanhf(d * s.y + b3[1]);
    float4 o;
    o.x = h0 * Wc[0] + h1 * Wc[4] + bc[0];
    o.y = h0 * Wc[1] + h1 * Wc[5] + bc[1];
    o.z = h0 * Wc[2] + h1 * Wc[6] + bc[2];
    o.w = h0 * Wc[3] + h1 * Wc[7] + bc[3];
    ((float4*)out)[v] = o;
    ((float2*)(out + (size_t)n * 4))[v] = make_float2(h0, h1);
}

extern "C" void kernel_launch(void* const* d_in, const int* in_sizes, int n_in,
                              void* d_out, int out_size, void* d_ws, size_t ws_size,
                              hipStream_t stream) {
    const float* x  = (const float*)d_in[0];
    const int*   ei = (const int*)  d_in[1];
    const float* W1 = (const float*)d_in[2];
    const float* b1 = (const float*)d_in[3];
    const float* W2 = (const float*)d_in[4];
    const float* b2 = (const float*)d_in[5];
    const float* W3 = (const float*)d_in[6];
    const float* b3 = (const float*)d_in[7];
    const float* Wc = (const float*)d_in[8];
    const float* bc = (const float*)d_in[9];

    const size_t n = (size_t)(in_sizes[0] / 128);
    const int    E = in_sizes[1] / 2;
    const int* row = ei;       // destinations (segment ids)
    const int* col = ei + E;   // sources (gather)

    const int B     = (int)((n + 255) >> 8);
    const int nb_n  = (int)((n + 255) / 256);
    const int nb_e  = (E + 255) / 256;
    const int nb_mm = (int)((n * 64 + 255) / 256);
    const int nb_ov = OVF_CAP / 256;
    const int nb_p  = (E + CHUNK - 1) / CHUNK;

    int* ws = (int*)d_ws;

    // fast-path layout (ints):
    // pairs B*CAPB | U max(ceil(B*CAPB/4), 10n + B*SPLIT*1024) | dinv n | deg n |
    // curR B | curC B | ovfRc 1 | ovfCc 1 (+pad) | ovfR 2*OVF_CAP | ovfC OVF_CAP
    size_t uni = ((size_t)B * CAPB + 3) / 4;
    size_t td_plus_p = 10 * n + (size_t)B * SPLIT * 1024;
    if (uni < td_plus_p) uni = td_plus_p;
    size_t need_fast = ((size_t)B * CAPB + uni + 2 * n + 2 * (size_t)B + 4 + 3 * OVF_CAP) * 4 + 64;

    if (ws_size >= need_fast && n <= (1u << 24) && B <= NBMAX) {
        int*   pairs = ws;
        int*   U     = pairs + (size_t)B * CAPB;
        float* Td1   = (float*)U;                      // 4n
        float* Td2   = Td1 + 4 * n;                    // 4n
        float* Td3   = Td2 + 4 * n;                    // 2n
        float* P     = Td3 + 2 * n;                    // B*SPLIT*1024
        unsigned char* bufC8 = (unsigned char*)U;      // dead after histo (aliases Td)
        float* dinv  = (float*)(U + uni);              // n
        int*   deg   = (int*)(dinv + n);               // n
        int*   curR  = deg + n;                        // B
        int*   curC  = curR + B;                       // B
        int*   ovfRc = curC + B;                       // 1
        int*   ovfCc = ovfRc + 1;                      // 1
        int2*  ovfR  = (int2*)(ovfCc + 1);
        {   // ensure 8B alignment for int2
            size_t off = (size_t)(ovfCc + 1 - ws);
            if (off & 1) ovfR = (int2*)(ovfCc + 2);
        }
        int*   ovfC  = (int*)(ovfR + OVF_CAP);

        initc_kernel<<<(B + 255) / 256, 256, 0, stream>>>(curR, curC, ovfRc, ovfCc, B);
        part_kernel<<<nb_p, 256, 0, stream>>>(row, col, curR, curC, pairs, bufC8,
                                              ovfRc, ovfR, ovfCc, ovfC, B, E);
        histo_kernel<<<B, 256, 0, stream>>>(curC, bufC8, deg, (int)n);
        ovfc_deg_kernel<<<nb_ov, 256, 0, stream>>>(ovfCc, ovfC, deg);
        // bufC8 dead from here; Td + P region live.
        mm1_kernel<<<nb_mm, 256, 0, stream>>>(x, W1, deg, dinv, Td1, (int)n);

        aggp4_kernel<<<B * SPLIT, 256, 0, stream>>>(curR, pairs, (const float4*)Td1, P);
        merge1_kernel<<<nb_n, 256, 0, stream>>>(P, dinv, (const float4*)Td1, ovfRc, ovfR, b1, W2, Td2, (int)n);

        aggp4_kernel<<<B * SPLIT, 256, 0, stream>>>(curR, pairs, (const float4*)Td2, P);
        merge2_kernel<<<nb_n, 256, 0, stream>>>(P, dinv, (const float4*)Td2, ovfRc, ovfR, b2, W3, Td3, (int)n);

        aggp2_kernel<<<B * SPLIT, 256, 0, stream>>>(curR, pairs, (const float2*)Td3, P);
        merge3_kernel<<<nb_n, 256, 0, stream>>>(P, dinv, (const float2*)Td3, ovfRc, ovfR, b3, Wc, bc, (float*)d_out, (int)n);
    } else {
        // fallback: round-2 ELL path (proven)
        float* fws  = (float*)d_ws;
        float* A1   = fws;
        float* A2   = A1 + 4 * n;
        float* C3   = A2 + 4 * n;
        float* Bv   = C3 + 2 * n;
        float* Dv   = Bv + 4 * n;
        float* dinv = Dv + 2 * n;
        int*   cnt  = (int*)(dinv + n);
        int*   deg  = cnt + n;
        int*   ovfc = deg + n;
        int2*  ovf  = (int2*)(ovfc + 4);
        int*   slots = (int*)(ovf + OVF_CAP);

        long zc = (long)(9 * n + 4);
        zero_kernel<<<(int)((zc + 255) / 256), 256, 0, stream>>>((int*)Bv, zc);
        build_kernel<<<nb_e, 256, 0, stream>>>(row, col, deg, cnt, slots, ovfc, ovf, (int)n, E);
        fb_mm1<<<nb_mm, 256, 0, stream>>>(x, W1, deg, dinv, (float4*)A1, (int)n);
        ovf4_kernel<<<nb_ov, 256, 0, stream>>>(ovfc, ovf, (const float4*)A1, Bv);
        agg_node1<<<nb_n, 256, 0, stream>>>(cnt, slots, dinv, (const float4*)A1, (float4*)Bv, b1, W2, (float4*)A2, (int)n);
        ovf4_kernel<<<nb_ov, 256, 0, stream>>>(ovfc, ovf, (const float4*)A2, Bv);
        agg_node2<<<nb_n, 256, 0, stream>>>(cnt, slots, dinv, (const float4*)A2, (const float4*)Bv, b2, W3, (float2*)C3, (int)n);
        ovf2_kernel<<<nb_ov, 256, 0, stream>>>(ovfc, ovf, (const float2*)C3, Dv);
        agg_node3<<<nb_n, 256, 0, stream>>>(cnt, slots, dinv, (const float2*)C3, (const float2*)Dv, b3, Wc, bc, (float*)d_out, (int)n);
    }
}